// Round 2
// 281.756 us; speedup vs baseline: 1.1149x; 1.1149x over previous
//
#include <hip/hip_runtime.h>
#include <cstdint>
#include <climits>

static constexpr int DM   = 128;   // d_model
static constexpr int NCOL = 96;    // off columns
static constexpr int NATT = 32;
static constexpr int VOXC = 8;
static constexpr int CAP  = 32768;
static constexpr float MARGIN = 4.0f;  // screen margin in off-units (~13 sigma)

// ws layout (ints):
static constexpr int OFF_B     = 8;                   // B frags 24KB (6144 ints)
static constexpr int OFF_BP    = OFF_B + 24 * 64 * 4; // 6152: permuted b_off (96 floats)
static constexpr int OFF_CAND  = OFF_BP + 96;         // 6248: (layout kept; unused now)
static constexpr int OFF_FINAL = OFF_CAND + CAP;      // confirmed pt ids
static constexpr int OFF_BITS  = OFF_FINAL + CAP;     // exact bits per confirmed pt [n]

typedef __attribute__((ext_vector_type(8))) short bf16x8;
typedef __attribute__((ext_vector_type(4))) float f32x4;

// async global->LDS, 16B per lane. Global src is PER-LANE; LDS dest is
// wave-uniform base + lane*16 (m104). Swizzled layouts => swizzle the SOURCE.
__device__ __forceinline__ void gload_lds16(const void* g, void* l) {
  __builtin_amdgcn_global_load_lds(
      (__attribute__((address_space(1))) void*)(const_cast<void*>(g)),
      (__attribute__((address_space(3))) void*)l, 16, 0, 0);
}

__device__ inline unsigned f2bf_rne(float f) {  // fp32 -> bf16 bits, RNE
  unsigned u = __float_as_uint(f);
  return (u + 0x7fffu + ((u >> 16) & 1u)) >> 16;
}
// column permutation: tile u (0..5), frag col nn (0..15) <- original Woff col.
__device__ inline int colperm(int u, int nn) {
  return ((u & 1) * 16 + nn) * 3 + (u >> 1);
}

__global__ __launch_bounds__(256) void k_init(const float* __restrict__ Woff,
                                              const float* __restrict__ boff,
                                              int* __restrict__ ws) {
  int t = threadIdx.x;
  if (blockIdx.x == 0) {
    if (t < 3) { ws[t] = INT_MAX; ws[3 + t] = INT_MIN; }
    if (t == 6) ws[6] = 0;
    if (t == 7) ws[7] = 0;
    if (t < 96)
      reinterpret_cast<float*>(ws + OFF_BP)[t] = boff[colperm(t >> 4, t & 15)];
  }
  int idx = blockIdx.x * 256 + t;
  if (idx < 24 * 64) {
    int f = idx >> 6, l = idx & 63;
    int s = f / 6, u = f - 6 * s;       // kstep, ntile
    int quad = l >> 4, nn = l & 15;
    int col = colperm(u, nn);
    int k0 = s * 32 + quad * 8;
    int4 d;
    d.x = (int)((f2bf_rne(Woff[(k0 + 1) * NCOL + col]) << 16) | f2bf_rne(Woff[(k0 + 0) * NCOL + col]));
    d.y = (int)((f2bf_rne(Woff[(k0 + 3) * NCOL + col]) << 16) | f2bf_rne(Woff[(k0 + 2) * NCOL + col]));
    d.z = (int)((f2bf_rne(Woff[(k0 + 5) * NCOL + col]) << 16) | f2bf_rne(Woff[(k0 + 4) * NCOL + col]));
    d.w = (int)((f2bf_rne(Woff[(k0 + 7) * NCOL + col]) << 16) | f2bf_rne(Woff[(k0 + 6) * NCOL + col]));
    *reinterpret_cast<int4*>(ws + OFF_B + idx * 4) = d;
  }
}

__global__ __launch_bounds__(256) void k_minmax(const int* __restrict__ coords, int n,
                                                int* __restrict__ ws) {
  __shared__ int bmn[3], bmx[3];
  int t = threadIdx.x;
  if (t < 3) { bmn[t] = INT_MAX; bmx[t] = INT_MIN; }
  __syncthreads();
  int mn[3] = {INT_MAX, INT_MAX, INT_MAX};
  int mx[3] = {INT_MIN, INT_MIN, INT_MIN};
  for (int i = blockIdx.x * blockDim.x + t; i < n; i += gridDim.x * blockDim.x) {
#pragma unroll
    for (int d = 0; d < 3; ++d) {
      int v = coords[i * 3 + d];
      mn[d] = min(mn[d], v);
      mx[d] = max(mx[d], v);
    }
  }
#pragma unroll
  for (int d = 0; d < 3; ++d) {
    for (int off = 32; off > 0; off >>= 1) {
      mn[d] = min(mn[d], __shfl_xor(mn[d], off, 64));
      mx[d] = max(mx[d], __shfl_xor(mx[d], off, 64));
    }
  }
  if ((t & 63) == 0) {
#pragma unroll
    for (int d = 0; d < 3; ++d) {
      atomicMin(&bmn[d], mn[d]);
      atomicMax(&bmx[d], mx[d]);
    }
  }
  __syncthreads();
  if (t < 3) {
    atomicMin(&ws[t], bmn[t]);
    atomicMax(&ws[3 + t], bmx[t]);
  }
}

// bf16 MFMA point-screen, async-staged via global_load_lds, with the exact
// fp32 recheck fused in-block (q rows already bit-exact in LDS).
// LDS: B frags 24KB + q tile 32KB (XOR-swizzled rows) + queue ~0.7KB => 2 blocks/CU.
__global__ __launch_bounds__(256, 2) void k_screen(
    const float* __restrict__ q, const float* __restrict__ Woff,
    const float* __restrict__ boff, const float* __restrict__ bout,
    float* __restrict__ out, int n, int* __restrict__ ws) {
  __shared__ int4 bfr[24 * 64];        // 24 KB B fragments (linear)
  __shared__ float qlds[64 * DM];      // 32 KB q rows, byte b holds q[r][b ^ ((r&7)<<4)]
  __shared__ int candq[64];
  __shared__ int okbuf[96];
  __shared__ int candn;

  const int t = threadIdx.x;
  const int wave = t >> 6, lane = t & 63;
  const int base = blockIdx.x * 64;

  if (t == 0) candn = 0;

  // --- async stage B fragments: 24 chunks of 1KB, linear dest ---
  {
    const int4* gsrc = reinterpret_cast<const int4*>(ws + OFF_B);
#pragma unroll
    for (int j = 0; j < 6; ++j) {
      int c = wave * 6 + j;
      gload_lds16(gsrc + c * 64 + lane, &bfr[c * 64]);
    }
  }
  // --- async stage q tile: 32 chunks of 1KB (2 rows each). Source address is
  // XOR-pre-swizzled so the linear LDS write yields a swizzled layout (m173).
  // Swizzle permutes 16B granules within 128B lines -> HBM coalescing intact.
  {
    const char* qb = reinterpret_cast<const char*>(q);
#pragma unroll
    for (int j = 0; j < 8; ++j) {
      int c = wave * 8 + j;
      int lr = 2 * c + (lane >> 5);            // local row 0..63
      int gr = min(base + lr, n - 1);
      int b  = ((lane & 31) * 16) ^ ((lr & 7) << 4);
      gload_lds16(qb + (size_t)gr * 512 + b,
                  reinterpret_cast<char*>(qlds) + c * 1024);
    }
  }

  // --- prefill out rows with b_out while the LDS loads are in flight.
  // Non-temporal: don't evict q/attn weights from L2/L3 with 100MB of stores.
  {
    f32x4 bv = reinterpret_cast<const f32x4*>(bout)[t & 31];
    f32x4* o4 = reinterpret_cast<f32x4*>(out);
#pragma unroll
    for (int i2 = 0; i2 < 8; ++i2) {
      int i = t + i2 * 256;
      int row = base + (i >> 5);
      if (row < n)
        __builtin_nontemporal_store(bv, &o4[(size_t)row * 32 + (i & 31)]);
    }
  }

  const int m = lane & 15, quad = lane >> 4;
  const float* bp = reinterpret_cast<const float*>(ws + OFF_BP);
  f32x4 acc[6];
#pragma unroll
  for (int u = 0; u < 6; ++u) {
    float bv = bp[u * 16 + m];
    acc[u] = (f32x4){bv, bv, bv, bv};
  }
  const float rcs[3] = {(float)(ws[3] - ws[0]) * 0.5f,
                        (float)(ws[4] - ws[1]) * 0.5f,
                        (float)(ws[5] - ws[2]) * 0.5f};

  __syncthreads();  // compiler drains vmcnt(0) here -> all LDS stages complete

  // --- MFMA screen: A frags from swizzled LDS (conflict-free ds_read_b128) ---
  const int lrow = wave * 16 + m;
  const char* qrl = reinterpret_cast<const char*>(qlds) + (size_t)lrow * 512;
  const int swz = (lrow & 7) << 4;
#pragma unroll
  for (int s = 0; s < 4; ++s) {
    f32x4 x = *reinterpret_cast<const f32x4*>(qrl + ((s * 128 + quad * 32) ^ swz));
    f32x4 y = *reinterpret_cast<const f32x4*>(qrl + ((s * 128 + quad * 32 + 16) ^ swz));
    union { int4 i; bf16x8 h; } A;  // truncation pack (hi16), margin covers it
    A.i.x = (int)((__float_as_uint(x.y) & 0xffff0000u) | (__float_as_uint(x.x) >> 16));
    A.i.y = (int)((__float_as_uint(x.w) & 0xffff0000u) | (__float_as_uint(x.z) >> 16));
    A.i.z = (int)((__float_as_uint(y.y) & 0xffff0000u) | (__float_as_uint(y.x) >> 16));
    A.i.w = (int)((__float_as_uint(y.w) & 0xffff0000u) | (__float_as_uint(y.z) >> 16));
#pragma unroll
    for (int u = 0; u < 6; ++u) {
      union { int4 i; bf16x8 h; } B;
      B.i = bfr[(s * 6 + u) * 64 + lane];
      acc[u] = __builtin_amdgcn_mfma_f32_16x16x32_bf16(A.h, B.h, acc[u], 0, 0, 0);
    }
  }

  // --- eval: D row = quad*4+r, col = u*16+m; triples (m, m+16) per lane ---
  unsigned long long b[4];
#pragma unroll
  for (int r = 0; r < 4; ++r) {
    bool any = false;
#pragma unroll
    for (int g = 0; g < 2; ++g) {
      bool ok = true;
#pragma unroll
      for (int jj = 0; jj < 3; ++jj) {
        float off = acc[2 * jj + g][r] * rcs[jj];
        ok = ok && (off > -1.0f - MARGIN) && (off < 8.0f + MARGIN);
      }
      any = any || ok;
    }
    b[r] = __ballot(any);
  }
  if (lane < 16) {
    int p = lane;
    int point = base + wave * 16 + p;
    unsigned long long bb = (p & 1) ? ((p & 2) ? b[3] : b[1])
                                    : ((p & 2) ? b[2] : b[0]);
    if (point < n && ((bb >> ((p >> 2) * 16)) & 0xffffull)) {
      int pos = atomicAdd(&candn, 1);
      candq[pos] = wave * 16 + p;   // local row; pt = base + lr. max 64, in-bounds
    }
  }
  __syncthreads();

  // --- fused exact fp32 recheck of this block's candidates (rare: ~0.3/block).
  // q read from LDS is bit-exact fp32; FMA order identical to prior k_recheck.
  const int C = candn;
  for (int ci = 0; ci < C; ++ci) {
    const int lr = candq[ci];
    const int pt = base + lr;
    if (t < 96) {
      const char* qr = reinterpret_cast<const char*>(qlds) + (size_t)lr * 512;
      const int sz = (lr & 7) << 4;
      const float rcf = (float)(ws[3 + t % 3] - ws[t % 3]);
      float a = boff[t];
      for (int k = 0; k < DM; ++k) {
        float qv = *reinterpret_cast<const float*>(qr + ((k * 4) ^ sz));
        a = fmaf(qv, Woff[k * NCOL + t], a);
      }
      int oi = (int)(a * rcf * 0.5f);
      okbuf[t] = (oi >= 0) && (oi < VOXC);
    }
    __syncthreads();
    if (t < 32) {
      bool mt = okbuf[3 * t] && okbuf[3 * t + 1] && okbuf[3 * t + 2];
      unsigned long long bb2 = __ballot(mt);
      if (t == 0) {
        unsigned bits32 = (unsigned)bb2;
        if (bits32) {
          ws[OFF_BITS + pt] = (int)bits32;
          int pos = atomicAdd(&ws[7], 1);
          if (pos < CAP) ws[OFF_FINAL + pos] = pt;
        }
      }
    }
    __syncthreads();
  }
}

// For each confirmed point: attn softmax, lazy value row, epilogue row add.
__global__ __launch_bounds__(64) void k_active(
    const float* __restrict__ q, const float* __restrict__ vfea,
    const int* __restrict__ coords,
    const float* __restrict__ Wattn, const float* __restrict__ battn,
    const float* __restrict__ Wval, const float* __restrict__ bval,
    const float* __restrict__ Wout,
    float* __restrict__ out, int n, const int* __restrict__ ws) {
  const int lane = threadIdx.x;  // block = 1 wave
  const int count = min(ws[7], CAP);
  const int mn0 = ws[0], mn1 = ws[1], mn2 = ws[2];
  const float rv0 = (float)((ws[3] - mn0) / VOXC + 1);
  const float rv1 = (float)((ws[4] - mn1) / VOXC + 1);
  const int* bits_arr = ws + OFF_BITS;

  for (int i = blockIdx.x; i < count; i += gridDim.x) {
    int pt = ws[OFF_FINAL + i];
    unsigned int bits = (unsigned int)bits_arr[pt];

    float i0 = (float)(coords[pt * 3 + 0] - mn0) * 0.125f;
    float i1 = (float)(coords[pt * 3 + 1] - mn1) * 0.125f;
    float i2 = (float)(coords[pt * 3 + 2] - mn2) * 0.125f;
    float flat = i0 * rv1 * rv0 + i1 * rv0 + i2;
    int g = (int)floorf(flat);
    g = min(max(g, 0), n - 1);

    const float* qrow = q + (size_t)pt * DM;

    float w_h = 0.0f;
    if (lane < NATT) {
      float acc = battn[lane];
      for (int k = 0; k < DM; ++k) acc = fmaf(qrow[k], Wattn[k * NATT + lane], acc);
      float mx = acc;
      mx = fmaxf(mx, __shfl_xor(mx, 1, 4));
      mx = fmaxf(mx, __shfl_xor(mx, 2, 4));
      float e = expf(acc - mx);
      float s = e;
      s += __shfl_xor(s, 1, 4);
      s += __shfl_xor(s, 2, 4);
      float a = e / s;
      float am = ((bits >> lane) & 1u) ? a : 0.0f;
      float w = am;
      w += __shfl_xor(w, 1, 4);
      w += __shfl_xor(w, 2, 4);
      w_h = w;
    }

    const float* vrow = vfea + (size_t)g * DM;
    float v0 = bval[lane], v1 = bval[lane + 64];
    for (int k = 0; k < DM; ++k) {
      float f = vrow[k];
      v0 = fmaf(f, Wval[k * DM + lane], v0);
      v1 = fmaf(f, Wval[k * DM + lane + 64], v1);
    }
    float wh0 = __shfl(w_h, (lane >> 4) * 4, 64);
    float wh1 = __shfl(w_h, ((lane >> 4) + 4) * 4, 64);
    float o0 = wh0 * v0;
    float o1 = wh1 * v1;

    float s0 = 0.0f, s1 = 0.0f;
    for (int d = 0; d < 64; ++d) {
      float od = __shfl(o0, d, 64);
      s0 = fmaf(od, Wout[d * DM + lane], s0);
      s1 = fmaf(od, Wout[d * DM + lane + 64], s1);
    }
    for (int d = 0; d < 64; ++d) {
      float od = __shfl(o1, d, 64);
      s0 = fmaf(od, Wout[(d + 64) * DM + lane], s0);
      s1 = fmaf(od, Wout[(d + 64) * DM + lane + 64], s1);
    }
    out[(size_t)pt * DM + lane] += s0;
    out[(size_t)pt * DM + lane + 64] += s1;
  }
}

extern "C" void kernel_launch(void* const* d_in, const int* in_sizes, int n_in,
                              void* d_out, int out_size, void* d_ws, size_t ws_size,
                              hipStream_t stream) {
  const float* q     = (const float*)d_in[0];
  const float* vfea  = (const float*)d_in[1];
  const int*   coords= (const int*)d_in[2];
  const float* Woff  = (const float*)d_in[3];
  const float* boff  = (const float*)d_in[4];
  const float* Wattn = (const float*)d_in[5];
  const float* battn = (const float*)d_in[6];
  const float* Wval  = (const float*)d_in[7];
  const float* bval  = (const float*)d_in[8];
  const float* Wout  = (const float*)d_in[9];
  const float* bout  = (const float*)d_in[10];
  float* out = (float*)d_out;
  int n = in_sizes[0] / DM;
  int* ws = (int*)d_ws;

  k_init<<<8, 256, 0, stream>>>(Woff, boff, ws);
  k_minmax<<<128, 256, 0, stream>>>(coords, n, ws);
  k_screen<<<(n + 63) / 64, 256, 0, stream>>>(q, Woff, boff, bout, out, n, ws);
  k_active<<<256, 64, 0, stream>>>(q, vfea, coords, Wattn, battn, Wval, bval, Wout, out, n, ws);
}